// Round 11
// baseline (213.842 us; speedup 1.0000x reference)
//
#include <hip/hip_runtime.h>

#define N_NODES 100000
#define N_EDGES 1600000
#define IN_C 128
#define HID_C 128
#define OUT_C 64

#define SH 8                 // bucket = dst >> 8 (256 nodes/bucket)
#define NBKT 391             // ceil(100000/256)
#define CAP 4608             // bucket capacity: mean 4096 + 8 sigma
#define EPB 2048             // edges per block in phase A
#define EPT 8                // EPB / 256

typedef __attribute__((ext_vector_type(8))) short bf16x8;
typedef __attribute__((ext_vector_type(4))) float f32x4;

// ---- bf16 helpers ----
static __device__ __forceinline__ unsigned f2bf(float f) {
  union { float f; unsigned u; } v; v.f = f;
  unsigned r = v.u + 0x7fffu + ((v.u >> 16) & 1u);
  return r >> 16;
}
static __device__ __forceinline__ float bf2f(unsigned hu) {
  union { unsigned u; float f; } v; v.u = hu << 16; return v.f;
}
static __device__ __forceinline__ float bflo(unsigned u) {
  union { unsigned u; float f; } v; v.u = u << 16; return v.f;
}
static __device__ __forceinline__ float bfhi(unsigned u) {
  union { unsigned u; float f; } v; v.u = u & 0xffff0000u; return v.f;
}

// ---------------- phase A: LDS-reorder radix partition by dst-bucket ----------------

__global__ __launch_bounds__(256) void k_partA(const int* __restrict__ src,
                                               const int* __restrict__ dst,
                                               int* __restrict__ bcnt,
                                               unsigned* __restrict__ tmp, int e) {
  __shared__ unsigned stage[EPB];        // 8 KB
  __shared__ unsigned short bid[EPB];    // 4 KB
  __shared__ int hist[NBKT];
  __shared__ int lstart[NBKT];
  __shared__ int base[NBKT];
  __shared__ int ps[256];
  const int t = threadIdx.x;
  const int e0 = blockIdx.x * EPB;
  const int m = (e0 + EPB < e ? EPB : e - e0);

  for (int i = t; i < NBKT; i += 256) hist[i] = 0;
  __syncthreads();

  int rsrc[EPT], rdst[EPT];
#pragma unroll
  for (int i = 0; i < EPT; ++i) {
    int idx = e0 + i * 256 + t;
    if (idx < e) {
      rsrc[i] = src[idx];
      rdst[i] = dst[idx];
      atomicAdd(&hist[rdst[i] >> SH], 1);
    }
  }
  __syncthreads();

  int a0 = (2 * t < NBKT) ? hist[2 * t] : 0;
  int a1 = (2 * t + 1 < NBKT) ? hist[2 * t + 1] : 0;
  ps[t] = a0 + a1;
  __syncthreads();
  for (int off = 1; off < 256; off <<= 1) {
    int add = (t >= off) ? ps[t - off] : 0;
    __syncthreads();
    ps[t] += add;
    __syncthreads();
  }
  int ex = ps[t] - (a0 + a1);
  if (2 * t < NBKT) lstart[2 * t] = ex;
  if (2 * t + 1 < NBKT) lstart[2 * t + 1] = ex + a0;

  for (int i = t; i < NBKT; i += 256) {
    int h = hist[i];
    base[i] = h ? atomicAdd(&bcnt[i], h) : 0;
    hist[i] = 0;
  }
  __syncthreads();

#pragma unroll
  for (int i = 0; i < EPT; ++i) {
    int idx = e0 + i * 256 + t;
    if (idx < e) {
      int d = rdst[i];
      int b = d >> SH;
      int pos = lstart[b] + atomicAdd(&hist[b], 1);
      stage[pos] = (unsigned)rsrc[i] | ((unsigned)(d & 255) << 17);
      bid[pos] = (unsigned short)b;
    }
  }
  __syncthreads();

  for (int pos = t; pos < m; pos += 256) {
    int b = bid[pos];
    int slot = base[b] + (pos - lstart[b]);
    if (slot < CAP)  // 8-sigma safety clamp
      tmp[(size_t)b * CAP + slot] = stage[pos];
  }
}

// single-block exclusive scan of clamped bcnt -> bstart[0..NBKT]
__global__ __launch_bounds__(512) void k_bscan(const int* __restrict__ bcnt,
                                               int* __restrict__ bstart) {
  __shared__ int s[512];
  const int t = threadIdx.x;
  int v = 0;
  if (t < NBKT) {
    v = bcnt[t];
    if (v > CAP) v = CAP;
  }
  s[t] = v;
  __syncthreads();
  for (int off = 1; off < 512; off <<= 1) {
    int add = (t >= off) ? s[t - off] : 0;
    __syncthreads();
    s[t] += add;
    __syncthreads();
  }
  if (t <= NBKT) bstart[t] = s[t] - v;  // t==NBKT (v=0) gets the total
}

// fused: per-bucket histogram -> dis + rowptr (bstart + local prefix) -> col scatter
__global__ __launch_bounds__(256) void k_bucket(const unsigned* __restrict__ tmp,
                                                const int* __restrict__ bcnt,
                                                const int* __restrict__ bstart,
                                                int* __restrict__ rowptr,
                                                int* __restrict__ col,
                                                float* __restrict__ dis, int n) {
  __shared__ int h[256];
  __shared__ int s[256];
  const int b = blockIdx.x, t = threadIdx.x;
  h[t] = 0;
  __syncthreads();
  int m = bcnt[b];
  if (m > CAP) m = CAP;
  const unsigned* tb = tmp + (size_t)b * CAP;
  for (int j = t; j < m; j += 256)
    atomicAdd(&h[tb[j] >> 17], 1);
  __syncthreads();
  const int node = (b << SH) + t;
  const int v = h[t];
  if (node < n) dis[node] = rsqrtf((float)(v + 1));
  s[t] = v;
  __syncthreads();
  for (int off = 1; off < 256; off <<= 1) {
    int add = (t >= off) ? s[t - off] : 0;
    __syncthreads();
    s[t] += add;
    __syncthreads();
  }
  const int base = bstart[b];
  const int ex = s[t] - v;
  if (node < n) rowptr[node] = base + ex;
  if (b == 0 && t == 0) rowptr[n] = bstart[NBKT];
  __syncthreads();
  h[t] = base + ex;  // reuse h as scatter cursor
  __syncthreads();
  for (int j = t; j < m; j += 256) {
    unsigned u = tb[j];
    int pos = atomicAdd(&h[u >> 17], 1);
    col[pos] = (int)(u & 0x1FFFFu);
  }
}

// ---------------- weight prep: transpose + split-bf16 (W = hi + lo) ----------------

__global__ void k_prepW(const float* __restrict__ W1, const float* __restrict__ W2,
                        unsigned short* __restrict__ W1h, unsigned short* __restrict__ W1l,
                        unsigned short* __restrict__ W2h, unsigned short* __restrict__ W2l) {
  int i = blockIdx.x * blockDim.x + threadIdx.x;
  if (i < IN_C * HID_C) {
    int k = i >> 7, c = i & 127;
    float w = W1[i];
    unsigned hi = f2bf(w);
    W1h[c * 128 + k] = (unsigned short)hi;
    W1l[c * 128 + k] = (unsigned short)f2bf(w - bf2f(hi));
  }
  int j = i - IN_C * HID_C;
  if (j >= 0 && j < HID_C * OUT_C) {
    int k = j >> 6, c = j & 63;
    float w = W2[j];
    unsigned hi = f2bf(w);
    W2h[c * 128 + k] = (unsigned short)hi;
    W2l[c * 128 + k] = (unsigned short)f2bf(w - bf2f(hi));
  }
}

// ---------------- MFMA GEMM layer 1: Hb[slice][node][64ch] = bf16((X@W1)*dis) ----------------

__global__ __launch_bounds__(256) void k_mfma1(const float* __restrict__ X,
                                               const unsigned short* __restrict__ Wh,
                                               const unsigned short* __restrict__ Wl,
                                               const float* __restrict__ dis,
                                               unsigned short* __restrict__ Hb, int n) {
  __shared__ unsigned short xs[64 * 136];
  const int t = threadIdx.x;
  const int w = t >> 6, l = t & 63;
  const int lr = l & 15, lk = (l >> 4) * 8;
  const int row0 = blockIdx.x * 64;

  bf16x8 Bh[2][4], Bl[2][4];
#pragma unroll
  for (int c2 = 0; c2 < 2; ++c2)
#pragma unroll
    for (int kb = 0; kb < 4; ++kb) {
      int colw = w * 32 + c2 * 16 + lr;
      Bh[c2][kb] = *(const bf16x8*)&Wh[(size_t)colw * 128 + kb * 32 + lk];
      Bl[c2][kb] = *(const bf16x8*)&Wl[(size_t)colw * 128 + kb * 32 + lk];
    }

  for (int i = t; i < 64 * 32; i += 256) {
    int r = i >> 5, q = i & 31;
    float4 v = make_float4(0.f, 0.f, 0.f, 0.f);
    if (row0 + r < n) v = ((const float4*)(X + (size_t)(row0 + r) * IN_C))[q];
    unsigned p0 = f2bf(v.x) | (f2bf(v.y) << 16);
    unsigned p1 = f2bf(v.z) | (f2bf(v.w) << 16);
    *(uint2*)&xs[r * 136 + q * 4] = make_uint2(p0, p1);
  }
  __syncthreads();

#pragma unroll
  for (int rst = 0; rst < 4; ++rst) {
    bf16x8 a[4];
#pragma unroll
    for (int kb = 0; kb < 4; ++kb)
      a[kb] = *(const bf16x8*)&xs[(rst * 16 + lr) * 136 + kb * 32 + lk];
    f32x4 acc0 = (f32x4){0.f, 0.f, 0.f, 0.f};
    f32x4 acc1 = (f32x4){0.f, 0.f, 0.f, 0.f};
#pragma unroll
    for (int kb = 0; kb < 4; ++kb) {
      acc0 = __builtin_amdgcn_mfma_f32_16x16x32_bf16(a[kb], Bh[0][kb], acc0, 0, 0, 0);
      acc1 = __builtin_amdgcn_mfma_f32_16x16x32_bf16(a[kb], Bh[1][kb], acc1, 0, 0, 0);
      acc0 = __builtin_amdgcn_mfma_f32_16x16x32_bf16(a[kb], Bl[0][kb], acc0, 0, 0, 0);
      acc1 = __builtin_amdgcn_mfma_f32_16x16x32_bf16(a[kb], Bl[1][kb], acc1, 0, 0, 0);
    }
    const int rbase = row0 + rst * 16 + (l >> 4) * 4;
    float dv[4];
#pragma unroll
    for (int j = 0; j < 4; ++j) dv[j] = (rbase + j < n) ? dis[rbase + j] : 0.f;
#pragma unroll
    for (int c2 = 0; c2 < 2; ++c2) {
      int colw = w * 32 + c2 * 16 + lr;
      const int grp = colw >> 6;      // channel slice (64 ch each)
      const int within = colw & 63;
      const f32x4& acc = c2 ? acc1 : acc0;
#pragma unroll
      for (int j = 0; j < 4; ++j) {
        int row = rbase + j;
        if (row < n)
          Hb[((size_t)grp * n + row) * 64 + within] = (unsigned short)f2bf(acc[j] * dv[j]);
      }
    }
  }
}

// ---------------- MFMA GEMM layer 2 (weights register-resident; input g1 linear) --------

__global__ __launch_bounds__(256) void k_mfma2(const unsigned* __restrict__ G,
                                               const unsigned short* __restrict__ Wh,
                                               const unsigned short* __restrict__ Wl,
                                               const float* __restrict__ dis,
                                               unsigned short* __restrict__ Hs, int n) {
  __shared__ unsigned short xs[64 * 136];
  const int t = threadIdx.x;
  const int w = t >> 6, l = t & 63;
  const int lr = l & 15, lk = (l >> 4) * 8;
  const int row0 = blockIdx.x * 64;

  bf16x8 Bh[4], Bl[4];
#pragma unroll
  for (int kb = 0; kb < 4; ++kb) {
    int colw = w * 16 + lr;
    Bh[kb] = *(const bf16x8*)&Wh[(size_t)colw * 128 + kb * 32 + lk];
    Bl[kb] = *(const bf16x8*)&Wl[(size_t)colw * 128 + kb * 32 + lk];
  }

  for (int i = t; i < 64 * 32; i += 256) {
    int r = i >> 5, q = i & 31;
    uint2 v = make_uint2(0u, 0u);
    if (row0 + r < n) v = *(const uint2*)&G[(size_t)(row0 + r) * 64 + q * 2];
    *(uint2*)&xs[r * 136 + q * 4] = v;
  }
  __syncthreads();

#pragma unroll
  for (int rst = 0; rst < 4; ++rst) {
    bf16x8 a[4];
#pragma unroll
    for (int kb = 0; kb < 4; ++kb)
      a[kb] = *(const bf16x8*)&xs[(rst * 16 + lr) * 136 + kb * 32 + lk];
    f32x4 acc = (f32x4){0.f, 0.f, 0.f, 0.f};
#pragma unroll
    for (int kb = 0; kb < 4; ++kb) {
      acc = __builtin_amdgcn_mfma_f32_16x16x32_bf16(a[kb], Bh[kb], acc, 0, 0, 0);
      acc = __builtin_amdgcn_mfma_f32_16x16x32_bf16(a[kb], Bl[kb], acc, 0, 0, 0);
    }
    const int rbase = row0 + rst * 16 + (l >> 4) * 4;
    const int colw = w * 16 + lr;
#pragma unroll
    for (int j = 0; j < 4; ++j) {
      int row = rbase + j;
      if (row < n) Hs[(size_t)row * OUT_C + colw] =
          (unsigned short)f2bf(acc[j] * dis[row]);
    }
  }
}

// ---------------- aggregation layer 1: 2-way channel-sliced (XCD-parity pinned) --------
// slice g = blockIdx&1 (12.8 MB, served by 4 XCDs); 32 lanes/node, R6 loop shape.
// G output layout unchanged: [node][64 uints] of bf16x2 channel pairs.

__global__ __launch_bounds__(256) void k_agg128s(const unsigned* __restrict__ Hb,
                                                 const int* __restrict__ rowptr,
                                                 const int* __restrict__ col,
                                                 const float* __restrict__ dis,
                                                 const float* __restrict__ bias,
                                                 unsigned* __restrict__ G, int n) {
  const int bid = blockIdx.x;
  const int g = bid & 1;
  const int node = (bid >> 1) * 8 + (threadIdx.x >> 5);
  const int l = threadIdx.x & 31;
  if (node >= n) return;
  const unsigned* T = Hb + (size_t)g * n * 32;  // uint view of slice: 32 uints/node
  unsigned u = T[(size_t)node * 32 + l];
  float a0 = bflo(u), a1 = bfhi(u);
  int j = rowptr[node];
  const int end = rowptr[node + 1];
  for (; j + 8 <= end; j += 8) {
    int s0 = col[j], s1 = col[j + 1], s2 = col[j + 2], s3 = col[j + 3];
    int s4 = col[j + 4], s5 = col[j + 5], s6 = col[j + 6], s7 = col[j + 7];
    unsigned u0 = T[(size_t)s0 * 32 + l];
    unsigned u1 = T[(size_t)s1 * 32 + l];
    unsigned u2 = T[(size_t)s2 * 32 + l];
    unsigned u3 = T[(size_t)s3 * 32 + l];
    unsigned u4 = T[(size_t)s4 * 32 + l];
    unsigned u5 = T[(size_t)s5 * 32 + l];
    unsigned u6 = T[(size_t)s6 * 32 + l];
    unsigned u7 = T[(size_t)s7 * 32 + l];
    a0 += ((bflo(u0) + bflo(u1)) + (bflo(u2) + bflo(u3))) +
          ((bflo(u4) + bflo(u5)) + (bflo(u6) + bflo(u7)));
    a1 += ((bfhi(u0) + bfhi(u1)) + (bfhi(u2) + bfhi(u3))) +
          ((bfhi(u4) + bfhi(u5)) + (bfhi(u6) + bfhi(u7)));
  }
  for (; j + 4 <= end; j += 4) {
    int s0 = col[j], s1 = col[j + 1], s2 = col[j + 2], s3 = col[j + 3];
    unsigned u0 = T[(size_t)s0 * 32 + l];
    unsigned u1 = T[(size_t)s1 * 32 + l];
    unsigned u2 = T[(size_t)s2 * 32 + l];
    unsigned u3 = T[(size_t)s3 * 32 + l];
    a0 += (bflo(u0) + bflo(u1)) + (bflo(u2) + bflo(u3));
    a1 += (bfhi(u0) + bfhi(u1)) + (bfhi(u2) + bfhi(u3));
  }
  for (; j < end; ++j) {
    unsigned uu = T[(size_t)col[j] * 32 + l];
    a0 += bflo(uu);
    a1 += bfhi(uu);
  }
  const float di = dis[node];
  const int c = g * 64 + l * 2;
  float r0 = fmaxf(fmaf(a0, di, bias[c]), 0.f);
  float r1 = fmaxf(fmaf(a1, di, bias[c + 1]), 0.f);
  G[(size_t)node * 64 + g * 32 + l] = f2bf(r0) | (f2bf(r1) << 16);
}

// ---------------- aggregation layer 2 (R6/R10 structure, unchanged) ----------------

__global__ __launch_bounds__(256) void k_agg64(const unsigned* __restrict__ Hs,
                                               const int* __restrict__ rowptr,
                                               const int* __restrict__ col,
                                               const float* __restrict__ dis,
                                               const float* __restrict__ bias,
                                               float* __restrict__ out, int n) {
  const int node = (blockIdx.x * blockDim.x + threadIdx.x) >> 5;
  const int l = threadIdx.x & 31;
  if (node >= n) return;
  unsigned u = Hs[(size_t)node * 32 + l];
  float a0 = bflo(u), a1 = bfhi(u);
  int j = rowptr[node];
  const int end = rowptr[node + 1];
  for (; j + 8 <= end; j += 8) {
    int s0 = col[j], s1 = col[j + 1], s2 = col[j + 2], s3 = col[j + 3];
    int s4 = col[j + 4], s5 = col[j + 5], s6 = col[j + 6], s7 = col[j + 7];
    unsigned u0 = Hs[(size_t)s0 * 32 + l];
    unsigned u1 = Hs[(size_t)s1 * 32 + l];
    unsigned u2 = Hs[(size_t)s2 * 32 + l];
    unsigned u3 = Hs[(size_t)s3 * 32 + l];
    unsigned u4 = Hs[(size_t)s4 * 32 + l];
    unsigned u5 = Hs[(size_t)s5 * 32 + l];
    unsigned u6 = Hs[(size_t)s6 * 32 + l];
    unsigned u7 = Hs[(size_t)s7 * 32 + l];
    a0 += ((bflo(u0) + bflo(u1)) + (bflo(u2) + bflo(u3))) +
          ((bflo(u4) + bflo(u5)) + (bflo(u6) + bflo(u7)));
    a1 += ((bfhi(u0) + bfhi(u1)) + (bfhi(u2) + bfhi(u3))) +
          ((bfhi(u4) + bfhi(u5)) + (bfhi(u6) + bfhi(u7)));
  }
  for (; j + 4 <= end; j += 4) {
    int s0 = col[j], s1 = col[j + 1], s2 = col[j + 2], s3 = col[j + 3];
    unsigned u0 = Hs[(size_t)s0 * 32 + l];
    unsigned u1 = Hs[(size_t)s1 * 32 + l];
    unsigned u2 = Hs[(size_t)s2 * 32 + l];
    unsigned u3 = Hs[(size_t)s3 * 32 + l];
    a0 += (bflo(u0) + bflo(u1)) + (bflo(u2) + bflo(u3));
    a1 += (bfhi(u0) + bfhi(u1)) + (bfhi(u2) + bfhi(u3));
  }
  for (; j < end; ++j) {
    unsigned uu = Hs[(size_t)col[j] * 32 + l];
    a0 += bflo(uu);
    a1 += bfhi(uu);
  }
  const float di = dis[node];
  const int c = l * 2;
  float r0 = fmaf(a0, di, bias[c]);
  float r1 = fmaf(a1, di, bias[c + 1]);
  *(float2*)&out[(size_t)node * 64 + c] = make_float2(r0, r1);
}

// ---------------- launch ----------------

extern "C" void kernel_launch(void* const* d_in, const int* in_sizes, int n_in,
                              void* d_out, int out_size, void* d_ws, size_t ws_size,
                              hipStream_t stream) {
  const float* x  = (const float*)d_in[0];
  const int*   ei = (const int*)d_in[1];
  const float* W1 = (const float*)d_in[2];
  const float* b1 = (const float*)d_in[3];
  const float* W2 = (const float*)d_in[4];
  const float* b2 = (const float*)d_in[5];
  float* out = (float*)d_out;

  const int N = N_NODES, E = N_EDGES;
  const int* esrc = ei;
  const int* edst = ei + E;

  char* w = (char*)d_ws;
  auto alloc = [&](size_t bytes) -> char* {
    char* p = w;
    w += (bytes + 255) & ~(size_t)255;
    return p;
  };
  float* dis          = (float*)alloc((size_t)N * 4);
  int* rowptr         = (int*)alloc((size_t)(N + 1) * 4);
  int* bcnt           = (int*)alloc((size_t)NBKT * 4);
  int* bstart         = (int*)alloc((size_t)(NBKT + 1) * 4);
  int* col            = (int*)alloc((size_t)E * 4);
  unsigned* tmp       = (unsigned*)alloc((size_t)NBKT * CAP * 4);       // 7.2 MB
  unsigned short* h1b = (unsigned short*)alloc((size_t)2 * N * 64 * 2); // 25.6 MB, 2 slices
  unsigned* g1        = (unsigned*)alloc((size_t)N * (HID_C / 2) * 4);  // 25.6 MB bf16x2
  unsigned short* h2s = (unsigned short*)alloc((size_t)N * OUT_C * 2);  // 12.8 MB
  unsigned short* W1h = (unsigned short*)alloc((size_t)IN_C * HID_C * 2);
  unsigned short* W1l = (unsigned short*)alloc((size_t)IN_C * HID_C * 2);
  unsigned short* W2h = (unsigned short*)alloc((size_t)HID_C * OUT_C * 2);
  unsigned short* W2l = (unsigned short*)alloc((size_t)HID_C * OUT_C * 2);

  // CSR build: partA -> bscan -> bucket (fused hist+scan+scatter)
  hipMemsetAsync(bcnt, 0, (size_t)NBKT * 4, stream);
  k_partA<<<(E + EPB - 1) / EPB, 256, 0, stream>>>(esrc, edst, bcnt, tmp, E);
  k_bscan<<<1, 512, 0, stream>>>(bcnt, bstart);
  k_bucket<<<NBKT, 256, 0, stream>>>(tmp, bcnt, bstart, rowptr, col, dis, N);
  k_prepW<<<(IN_C * HID_C + HID_C * OUT_C + 255) / 256, 256, 0, stream>>>(
      W1, W2, W1h, W1l, W2h, W2l);

  // layer 1: sliced gather table, parity-pinned channel slices
  k_mfma1<<<(N + 63) / 64, 256, 0, stream>>>(x, W1h, W1l, dis, h1b, N);
  k_agg128s<<<((N + 7) / 8) * 2, 256, 0, stream>>>((const unsigned*)h1b, rowptr, col,
                                                   dis, b1, g1, N);
  // layer 2
  k_mfma2<<<(N + 63) / 64, 256, 0, stream>>>(g1, W2h, W2l, dis, h2s, N);
  k_agg64<<<(N * 32 + 255) / 256, 256, 0, stream>>>((const unsigned*)h2s, rowptr, col,
                                                    dis, b2, out, N);
}

// Round 12
// 209.804 us; speedup vs baseline: 1.0192x; 1.0192x over previous
//
#include <hip/hip_runtime.h>

#define N_NODES 100000
#define N_EDGES 1600000
#define IN_C 128
#define HID_C 128
#define OUT_C 64

#define SH 8                 // bucket = dst >> 8 (256 nodes/bucket)
#define NBKT 391             // ceil(100000/256)
#define CAP 4608             // bucket capacity: mean 4096 + 8 sigma
#define EPB 2048             // edges per block in phase A
#define EPT 8                // EPB / 256

typedef __attribute__((ext_vector_type(8))) short bf16x8;
typedef __attribute__((ext_vector_type(4))) float f32x4;

// ---- bf16 helpers ----
static __device__ __forceinline__ unsigned f2bf(float f) {
  union { float f; unsigned u; } v; v.f = f;
  unsigned r = v.u + 0x7fffu + ((v.u >> 16) & 1u);
  return r >> 16;
}
static __device__ __forceinline__ float bf2f(unsigned hu) {
  union { unsigned u; float f; } v; v.u = hu << 16; return v.f;
}
static __device__ __forceinline__ float bflo(unsigned u) {
  union { unsigned u; float f; } v; v.u = u << 16; return v.f;
}
static __device__ __forceinline__ float bfhi(unsigned u) {
  union { unsigned u; float f; } v; v.u = u & 0xffff0000u; return v.f;
}

// ---------------- phase A: LDS-reorder radix partition by dst-bucket ----------------

__global__ __launch_bounds__(256) void k_partA(const int* __restrict__ src,
                                               const int* __restrict__ dst,
                                               int* __restrict__ bcnt,
                                               unsigned* __restrict__ tmp, int e) {
  __shared__ unsigned stage[EPB];        // 8 KB
  __shared__ unsigned short bid[EPB];    // 4 KB
  __shared__ int hist[NBKT];
  __shared__ int lstart[NBKT];
  __shared__ int base[NBKT];
  __shared__ int ps[256];
  const int t = threadIdx.x;
  const int e0 = blockIdx.x * EPB;
  const int m = (e0 + EPB < e ? EPB : e - e0);

  for (int i = t; i < NBKT; i += 256) hist[i] = 0;
  __syncthreads();

  int rsrc[EPT], rdst[EPT];
#pragma unroll
  for (int i = 0; i < EPT; ++i) {
    int idx = e0 + i * 256 + t;
    if (idx < e) {
      rsrc[i] = src[idx];
      rdst[i] = dst[idx];
      atomicAdd(&hist[rdst[i] >> SH], 1);
    }
  }
  __syncthreads();

  int a0 = (2 * t < NBKT) ? hist[2 * t] : 0;
  int a1 = (2 * t + 1 < NBKT) ? hist[2 * t + 1] : 0;
  ps[t] = a0 + a1;
  __syncthreads();
  for (int off = 1; off < 256; off <<= 1) {
    int add = (t >= off) ? ps[t - off] : 0;
    __syncthreads();
    ps[t] += add;
    __syncthreads();
  }
  int ex = ps[t] - (a0 + a1);
  if (2 * t < NBKT) lstart[2 * t] = ex;
  if (2 * t + 1 < NBKT) lstart[2 * t + 1] = ex + a0;

  for (int i = t; i < NBKT; i += 256) {
    int h = hist[i];
    base[i] = h ? atomicAdd(&bcnt[i], h) : 0;
    hist[i] = 0;
  }
  __syncthreads();

#pragma unroll
  for (int i = 0; i < EPT; ++i) {
    int idx = e0 + i * 256 + t;
    if (idx < e) {
      int d = rdst[i];
      int b = d >> SH;
      int pos = lstart[b] + atomicAdd(&hist[b], 1);
      stage[pos] = (unsigned)rsrc[i] | ((unsigned)(d & 255) << 17);
      bid[pos] = (unsigned short)b;
    }
  }
  __syncthreads();

  for (int pos = t; pos < m; pos += 256) {
    int b = bid[pos];
    int slot = base[b] + (pos - lstart[b]);
    if (slot < CAP)  // 8-sigma safety clamp
      tmp[(size_t)b * CAP + slot] = stage[pos];
  }
}

// single-block exclusive scan of clamped bcnt -> bstart[0..NBKT]
__global__ __launch_bounds__(512) void k_bscan(const int* __restrict__ bcnt,
                                               int* __restrict__ bstart) {
  __shared__ int s[512];
  const int t = threadIdx.x;
  int v = 0;
  if (t < NBKT) {
    v = bcnt[t];
    if (v > CAP) v = CAP;
  }
  s[t] = v;
  __syncthreads();
  for (int off = 1; off < 512; off <<= 1) {
    int add = (t >= off) ? s[t - off] : 0;
    __syncthreads();
    s[t] += add;
    __syncthreads();
  }
  if (t <= NBKT) bstart[t] = s[t] - v;  // t==NBKT (v=0) gets the total
}

// fused: per-bucket histogram -> dis + rowptr (bstart + local prefix) -> col scatter
__global__ __launch_bounds__(256) void k_bucket(const unsigned* __restrict__ tmp,
                                                const int* __restrict__ bcnt,
                                                const int* __restrict__ bstart,
                                                int* __restrict__ rowptr,
                                                int* __restrict__ col,
                                                float* __restrict__ dis, int n) {
  __shared__ int h[256];
  __shared__ int s[256];
  const int b = blockIdx.x, t = threadIdx.x;
  h[t] = 0;
  __syncthreads();
  int m = bcnt[b];
  if (m > CAP) m = CAP;
  const unsigned* tb = tmp + (size_t)b * CAP;
  for (int j = t; j < m; j += 256)
    atomicAdd(&h[tb[j] >> 17], 1);
  __syncthreads();
  const int node = (b << SH) + t;
  const int v = h[t];
  if (node < n) dis[node] = rsqrtf((float)(v + 1));
  s[t] = v;
  __syncthreads();
  for (int off = 1; off < 256; off <<= 1) {
    int add = (t >= off) ? s[t - off] : 0;
    __syncthreads();
    s[t] += add;
    __syncthreads();
  }
  const int base = bstart[b];
  const int ex = s[t] - v;
  if (node < n) rowptr[node] = base + ex;
  if (b == 0 && t == 0) rowptr[n] = bstart[NBKT];
  __syncthreads();
  h[t] = base + ex;  // reuse h as scatter cursor
  __syncthreads();
  for (int j = t; j < m; j += 256) {
    unsigned u = tb[j];
    int pos = atomicAdd(&h[u >> 17], 1);
    col[pos] = (int)(u & 0x1FFFFu);
  }
}

// ---------------- weight prep: transpose + split-bf16 (W = hi + lo) ----------------

__global__ void k_prepW(const float* __restrict__ W1, const float* __restrict__ W2,
                        unsigned short* __restrict__ W1h, unsigned short* __restrict__ W1l,
                        unsigned short* __restrict__ W2h, unsigned short* __restrict__ W2l) {
  int i = blockIdx.x * blockDim.x + threadIdx.x;
  if (i < IN_C * HID_C) {
    int k = i >> 7, c = i & 127;
    float w = W1[i];
    unsigned hi = f2bf(w);
    W1h[c * 128 + k] = (unsigned short)hi;
    W1l[c * 128 + k] = (unsigned short)f2bf(w - bf2f(hi));
  }
  int j = i - IN_C * HID_C;
  if (j >= 0 && j < HID_C * OUT_C) {
    int k = j >> 6, c = j & 63;
    float w = W2[j];
    unsigned hi = f2bf(w);
    W2h[c * 128 + k] = (unsigned short)hi;
    W2l[c * 128 + k] = (unsigned short)f2bf(w - bf2f(hi));
  }
}

// ---------------- MFMA GEMM layer 1 (weights register-resident) ----------------

__global__ __launch_bounds__(256) void k_mfma1(const float* __restrict__ X,
                                               const unsigned short* __restrict__ Wh,
                                               const unsigned short* __restrict__ Wl,
                                               const float* __restrict__ dis,
                                               unsigned short* __restrict__ Hs, int n) {
  __shared__ unsigned short xs[64 * 136];
  const int t = threadIdx.x;
  const int w = t >> 6, l = t & 63;
  const int lr = l & 15, lk = (l >> 4) * 8;
  const int row0 = blockIdx.x * 64;

  bf16x8 Bh[2][4], Bl[2][4];
#pragma unroll
  for (int c2 = 0; c2 < 2; ++c2)
#pragma unroll
    for (int kb = 0; kb < 4; ++kb) {
      int colw = w * 32 + c2 * 16 + lr;
      Bh[c2][kb] = *(const bf16x8*)&Wh[(size_t)colw * 128 + kb * 32 + lk];
      Bl[c2][kb] = *(const bf16x8*)&Wl[(size_t)colw * 128 + kb * 32 + lk];
    }

  for (int i = t; i < 64 * 32; i += 256) {
    int r = i >> 5, q = i & 31;
    float4 v = make_float4(0.f, 0.f, 0.f, 0.f);
    if (row0 + r < n) v = ((const float4*)(X + (size_t)(row0 + r) * IN_C))[q];
    unsigned p0 = f2bf(v.x) | (f2bf(v.y) << 16);
    unsigned p1 = f2bf(v.z) | (f2bf(v.w) << 16);
    *(uint2*)&xs[r * 136 + q * 4] = make_uint2(p0, p1);
  }
  __syncthreads();

#pragma unroll
  for (int rst = 0; rst < 4; ++rst) {
    bf16x8 a[4];
#pragma unroll
    for (int kb = 0; kb < 4; ++kb)
      a[kb] = *(const bf16x8*)&xs[(rst * 16 + lr) * 136 + kb * 32 + lk];
    f32x4 acc0 = (f32x4){0.f, 0.f, 0.f, 0.f};
    f32x4 acc1 = (f32x4){0.f, 0.f, 0.f, 0.f};
#pragma unroll
    for (int kb = 0; kb < 4; ++kb) {
      acc0 = __builtin_amdgcn_mfma_f32_16x16x32_bf16(a[kb], Bh[0][kb], acc0, 0, 0, 0);
      acc1 = __builtin_amdgcn_mfma_f32_16x16x32_bf16(a[kb], Bh[1][kb], acc1, 0, 0, 0);
      acc0 = __builtin_amdgcn_mfma_f32_16x16x32_bf16(a[kb], Bl[0][kb], acc0, 0, 0, 0);
      acc1 = __builtin_amdgcn_mfma_f32_16x16x32_bf16(a[kb], Bl[1][kb], acc1, 0, 0, 0);
    }
    const int rbase = row0 + rst * 16 + (l >> 4) * 4;
    float dv[4];
#pragma unroll
    for (int j = 0; j < 4; ++j) dv[j] = (rbase + j < n) ? dis[rbase + j] : 0.f;
#pragma unroll
    for (int c2 = 0; c2 < 2; ++c2) {
      int colw = w * 32 + c2 * 16 + lr;
      const f32x4& acc = c2 ? acc1 : acc0;
#pragma unroll
      for (int j = 0; j < 4; ++j) {
        int row = rbase + j;
        if (row < n) Hs[(size_t)row * HID_C + colw] = (unsigned short)f2bf(acc[j] * dv[j]);
      }
    }
  }
}

// ---------------- MFMA GEMM layer 2 (weights register-resident) ----------------

__global__ __launch_bounds__(256) void k_mfma2(const unsigned* __restrict__ G,
                                               const unsigned short* __restrict__ Wh,
                                               const unsigned short* __restrict__ Wl,
                                               const float* __restrict__ dis,
                                               unsigned short* __restrict__ Hs, int n) {
  __shared__ unsigned short xs[64 * 136];
  const int t = threadIdx.x;
  const int w = t >> 6, l = t & 63;
  const int lr = l & 15, lk = (l >> 4) * 8;
  const int row0 = blockIdx.x * 64;

  bf16x8 Bh[4], Bl[4];
#pragma unroll
  for (int kb = 0; kb < 4; ++kb) {
    int colw = w * 16 + lr;
    Bh[kb] = *(const bf16x8*)&Wh[(size_t)colw * 128 + kb * 32 + lk];
    Bl[kb] = *(const bf16x8*)&Wl[(size_t)colw * 128 + kb * 32 + lk];
  }

  for (int i = t; i < 64 * 32; i += 256) {
    int r = i >> 5, q = i & 31;
    uint2 v = make_uint2(0u, 0u);
    if (row0 + r < n) v = *(const uint2*)&G[(size_t)(row0 + r) * 64 + q * 2];
    *(uint2*)&xs[r * 136 + q * 4] = v;
  }
  __syncthreads();

#pragma unroll
  for (int rst = 0; rst < 4; ++rst) {
    bf16x8 a[4];
#pragma unroll
    for (int kb = 0; kb < 4; ++kb)
      a[kb] = *(const bf16x8*)&xs[(rst * 16 + lr) * 136 + kb * 32 + lk];
    f32x4 acc = (f32x4){0.f, 0.f, 0.f, 0.f};
#pragma unroll
    for (int kb = 0; kb < 4; ++kb) {
      acc = __builtin_amdgcn_mfma_f32_16x16x32_bf16(a[kb], Bh[kb], acc, 0, 0, 0);
      acc = __builtin_amdgcn_mfma_f32_16x16x32_bf16(a[kb], Bl[kb], acc, 0, 0, 0);
    }
    const int rbase = row0 + rst * 16 + (l >> 4) * 4;
    const int colw = w * 16 + lr;
#pragma unroll
    for (int j = 0; j < 4; ++j) {
      int row = rbase + j;
      if (row < n) Hs[(size_t)row * OUT_C + colw] =
          (unsigned short)f2bf(acc[j] * dis[row]);
    }
  }
}

// ---------------- aggregation (best measured structure; at load-path roofline) --------
// out[i] = dis[i]*(h'[i] + sum h'[s]) + b  [, relu]

__global__ __launch_bounds__(256) void k_agg128(const unsigned* __restrict__ Hs,
                                                const int* __restrict__ rowptr,
                                                const int* __restrict__ col,
                                                const float* __restrict__ dis,
                                                const float* __restrict__ bias,
                                                unsigned* __restrict__ G, int n) {
  const int node = (blockIdx.x * blockDim.x + threadIdx.x) >> 6;
  const int lane = threadIdx.x & 63;
  if (node >= n) return;
  unsigned u = Hs[(size_t)node * 64 + lane];
  float a0 = bflo(u), a1 = bfhi(u);
  int j = rowptr[node];
  const int end = rowptr[node + 1];
  for (; j + 8 <= end; j += 8) {
    int s0 = col[j], s1 = col[j + 1], s2 = col[j + 2], s3 = col[j + 3];
    int s4 = col[j + 4], s5 = col[j + 5], s6 = col[j + 6], s7 = col[j + 7];
    unsigned u0 = Hs[(size_t)s0 * 64 + lane];
    unsigned u1 = Hs[(size_t)s1 * 64 + lane];
    unsigned u2 = Hs[(size_t)s2 * 64 + lane];
    unsigned u3 = Hs[(size_t)s3 * 64 + lane];
    unsigned u4 = Hs[(size_t)s4 * 64 + lane];
    unsigned u5 = Hs[(size_t)s5 * 64 + lane];
    unsigned u6 = Hs[(size_t)s6 * 64 + lane];
    unsigned u7 = Hs[(size_t)s7 * 64 + lane];
    a0 += ((bflo(u0) + bflo(u1)) + (bflo(u2) + bflo(u3))) +
          ((bflo(u4) + bflo(u5)) + (bflo(u6) + bflo(u7)));
    a1 += ((bfhi(u0) + bfhi(u1)) + (bfhi(u2) + bfhi(u3))) +
          ((bfhi(u4) + bfhi(u5)) + (bfhi(u6) + bfhi(u7)));
  }
  for (; j + 4 <= end; j += 4) {
    int s0 = col[j], s1 = col[j + 1], s2 = col[j + 2], s3 = col[j + 3];
    unsigned u0 = Hs[(size_t)s0 * 64 + lane];
    unsigned u1 = Hs[(size_t)s1 * 64 + lane];
    unsigned u2 = Hs[(size_t)s2 * 64 + lane];
    unsigned u3 = Hs[(size_t)s3 * 64 + lane];
    a0 += (bflo(u0) + bflo(u1)) + (bflo(u2) + bflo(u3));
    a1 += (bfhi(u0) + bfhi(u1)) + (bfhi(u2) + bfhi(u3));
  }
  for (; j < end; ++j) {
    unsigned uu = Hs[(size_t)col[j] * 64 + lane];
    a0 += bflo(uu);
    a1 += bfhi(uu);
  }
  const float di = dis[node];
  const int c = lane * 2;
  float r0 = fmaxf(fmaf(a0, di, bias[c]), 0.f);
  float r1 = fmaxf(fmaf(a1, di, bias[c + 1]), 0.f);
  G[(size_t)node * 64 + lane] = f2bf(r0) | (f2bf(r1) << 16);
}

__global__ __launch_bounds__(256) void k_agg64(const unsigned* __restrict__ Hs,
                                               const int* __restrict__ rowptr,
                                               const int* __restrict__ col,
                                               const float* __restrict__ dis,
                                               const float* __restrict__ bias,
                                               float* __restrict__ out, int n) {
  const int node = (blockIdx.x * blockDim.x + threadIdx.x) >> 5;
  const int l = threadIdx.x & 31;
  if (node >= n) return;
  unsigned u = Hs[(size_t)node * 32 + l];
  float a0 = bflo(u), a1 = bfhi(u);
  int j = rowptr[node];
  const int end = rowptr[node + 1];
  for (; j + 8 <= end; j += 8) {
    int s0 = col[j], s1 = col[j + 1], s2 = col[j + 2], s3 = col[j + 3];
    int s4 = col[j + 4], s5 = col[j + 5], s6 = col[j + 6], s7 = col[j + 7];
    unsigned u0 = Hs[(size_t)s0 * 32 + l];
    unsigned u1 = Hs[(size_t)s1 * 32 + l];
    unsigned u2 = Hs[(size_t)s2 * 32 + l];
    unsigned u3 = Hs[(size_t)s3 * 32 + l];
    unsigned u4 = Hs[(size_t)s4 * 32 + l];
    unsigned u5 = Hs[(size_t)s5 * 32 + l];
    unsigned u6 = Hs[(size_t)s6 * 32 + l];
    unsigned u7 = Hs[(size_t)s7 * 32 + l];
    a0 += ((bflo(u0) + bflo(u1)) + (bflo(u2) + bflo(u3))) +
          ((bflo(u4) + bflo(u5)) + (bflo(u6) + bflo(u7)));
    a1 += ((bfhi(u0) + bfhi(u1)) + (bfhi(u2) + bfhi(u3))) +
          ((bfhi(u4) + bfhi(u5)) + (bfhi(u6) + bfhi(u7)));
  }
  for (; j + 4 <= end; j += 4) {
    int s0 = col[j], s1 = col[j + 1], s2 = col[j + 2], s3 = col[j + 3];
    unsigned u0 = Hs[(size_t)s0 * 32 + l];
    unsigned u1 = Hs[(size_t)s1 * 32 + l];
    unsigned u2 = Hs[(size_t)s2 * 32 + l];
    unsigned u3 = Hs[(size_t)s3 * 32 + l];
    a0 += (bflo(u0) + bflo(u1)) + (bflo(u2) + bflo(u3));
    a1 += (bfhi(u0) + bfhi(u1)) + (bfhi(u2) + bfhi(u3));
  }
  for (; j < end; ++j) {
    unsigned uu = Hs[(size_t)col[j] * 32 + l];
    a0 += bflo(uu);
    a1 += bfhi(uu);
  }
  const float di = dis[node];
  const int c = l * 2;
  float r0 = fmaf(a0, di, bias[c]);
  float r1 = fmaf(a1, di, bias[c + 1]);
  *(float2*)&out[(size_t)node * 64 + c] = make_float2(r0, r1);
}

// ---------------- launch ----------------

extern "C" void kernel_launch(void* const* d_in, const int* in_sizes, int n_in,
                              void* d_out, int out_size, void* d_ws, size_t ws_size,
                              hipStream_t stream) {
  const float* x  = (const float*)d_in[0];
  const int*   ei = (const int*)d_in[1];
  const float* W1 = (const float*)d_in[2];
  const float* b1 = (const float*)d_in[3];
  const float* W2 = (const float*)d_in[4];
  const float* b2 = (const float*)d_in[5];
  float* out = (float*)d_out;

  const int N = N_NODES, E = N_EDGES;
  const int* esrc = ei;
  const int* edst = ei + E;

  char* w = (char*)d_ws;
  auto alloc = [&](size_t bytes) -> char* {
    char* p = w;
    w += (bytes + 255) & ~(size_t)255;
    return p;
  };
  float* dis          = (float*)alloc((size_t)N * 4);
  int* rowptr         = (int*)alloc((size_t)(N + 1) * 4);
  int* bcnt           = (int*)alloc((size_t)NBKT * 4);
  int* bstart         = (int*)alloc((size_t)(NBKT + 1) * 4);
  int* col            = (int*)alloc((size_t)E * 4);
  unsigned* tmp       = (unsigned*)alloc((size_t)NBKT * CAP * 4);       // 7.2 MB
  unsigned short* h1s = (unsigned short*)alloc((size_t)N * HID_C * 2);  // 25.6 MB
  unsigned* g1        = (unsigned*)alloc((size_t)N * (HID_C / 2) * 4);  // 25.6 MB bf16x2
  unsigned short* h2s = (unsigned short*)alloc((size_t)N * OUT_C * 2);  // 12.8 MB
  unsigned short* W1h = (unsigned short*)alloc((size_t)IN_C * HID_C * 2);
  unsigned short* W1l = (unsigned short*)alloc((size_t)IN_C * HID_C * 2);
  unsigned short* W2h = (unsigned short*)alloc((size_t)HID_C * OUT_C * 2);
  unsigned short* W2l = (unsigned short*)alloc((size_t)HID_C * OUT_C * 2);

  // CSR build: partA -> bscan -> bucket (fused hist+scan+scatter)
  hipMemsetAsync(bcnt, 0, (size_t)NBKT * 4, stream);
  k_partA<<<(E + EPB - 1) / EPB, 256, 0, stream>>>(esrc, edst, bcnt, tmp, E);
  k_bscan<<<1, 512, 0, stream>>>(bcnt, bstart);
  k_bucket<<<NBKT, 256, 0, stream>>>(tmp, bcnt, bstart, rowptr, col, dis, N);
  k_prepW<<<(IN_C * HID_C + HID_C * OUT_C + 255) / 256, 256, 0, stream>>>(
      W1, W2, W1h, W1l, W2h, W2l);

  // layer 1
  k_mfma1<<<(N + 63) / 64, 256, 0, stream>>>(x, W1h, W1l, dis, h1s, N);
  k_agg128<<<(N * 64 + 255) / 256, 256, 0, stream>>>((const unsigned*)h1s, rowptr, col,
                                                     dis, b1, g1, N);
  // layer 2
  k_mfma2<<<(N + 63) / 64, 256, 0, stream>>>(g1, W2h, W2l, dis, h2s, N);
  k_agg64<<<(N * 32 + 255) / 256, 256, 0, stream>>>((const unsigned*)h2s, rowptr, col,
                                                    dis, b2, out, N);
}